// Round 1
// 489.756 us; speedup vs baseline: 1.1613x; 1.1613x over previous
//
#include <hip/hip_runtime.h>
#include <hip/hip_bf16.h>
#include <cstdint>

#define B_DIM 4096
#define H_DIM 2048
#define I_DIM 2048
#define K_DIM 4096   // combined = H + I
#define N4    8192   // 4 * H

typedef unsigned int u32;
typedef unsigned short u16;
typedef __attribute__((ext_vector_type(4))) float floatx4;
typedef __attribute__((ext_vector_type(8))) short bf16x8;
typedef __attribute__((ext_vector_type(8))) float f32x8;
typedef __attribute__((ext_vector_type(8))) __bf16 bfx8;

__device__ static inline void gload16(const void* g, void* l) {
    __builtin_amdgcn_global_load_lds(
        (const __attribute__((address_space(1))) u32*)g,
        (__attribute__((address_space(3))) u32*)l, 16, 0, 0);
}
__device__ static inline float fast_sig(float x) {
    return 1.f / (1.f + __expf(-x));
}
__device__ static inline float fast_tanh(float x) {
    float ax = fabsf(x);
    float t = __expf(-2.f * ax);
    float r = (1.f - t) / (1.f + t);
    return copysignf(r, x);
}

// ---------------------------------------------------------------------------
// Kernel 1: fp32 -> bf16 conversions, one dispatch, 8 elems/thread.
// CHANGE vs prev round: __builtin_convertvector -> v_cvt_pk_bf16_f32 (RNE),
// replacing ~32 integer-RNE VALU ops/thread with ~4.  Theory: convert was
// VALU-bound at ~1.4 TB/s; expect BW-bound now.
//  blocks [0, 8192):       comb[4096][4096] = bf16(concat([h_prev, x_t], 1))
//  blocks [8192, 24576):   wb[8192][4096]   = bf16(W), GATE-PERMUTED rows:
//    wb row n  <-  W_g row j:  row128 = n & 127, g = (row128>>4)&3,
//                              j = (n>>7)*32 + ((row128>>6)<<4) + (row128&15)
// ---------------------------------------------------------------------------
__global__ void convert_all(const float* __restrict__ h_prev, const float* __restrict__ x_t,
                            const float* __restrict__ Wf, const float* __restrict__ Wi,
                            const float* __restrict__ Wc, const float* __restrict__ Wo,
                            u16* __restrict__ comb, u16* __restrict__ wb) {
    const int bid = blockIdx.x;
    const float* src;
    u16* dst;
    if (bid < 8192) {
        int base = (bid * 256 + (int)threadIdx.x) * 8;   // < 2^24
        int row = base >> 12, col = base & 4095;
        src = (col < H_DIM) ? h_prev + (size_t)row * H_DIM + col
                            : x_t    + (size_t)row * I_DIM + (col - H_DIM);
        dst = comb + base;
    } else {
        long long base = ((long long)(bid - 8192) * 256 + threadIdx.x) * 8;
        int n = (int)(base >> 12), col = (int)(base & 4095);
        int row128 = n & 127;
        int g = (row128 >> 4) & 3;
        int j = (n >> 7) * 32 + ((row128 >> 6) << 4) + (row128 & 15);
        const float* W = (g == 0) ? Wf : (g == 1) ? Wi : (g == 2) ? Wc : Wo;
        src = W + (size_t)j * K_DIM + col;
        dst = wb + base;
    }
    float4 v0 = *(const float4*)src;
    float4 v1 = *(const float4*)(src + 4);
    f32x8 f = { v0.x, v0.y, v0.z, v0.w, v1.x, v1.y, v1.z, v1.w };
    *(bfx8*)dst = __builtin_convertvector(f, bfx8);   // v_cvt_pk_bf16_f32 (RNE)
}

// ---------------------------------------------------------------------------
// Kernel 2: fused GEMM + LSTM epilogue — counted-vmcnt deep-pipeline rewrite.
// 256x256 tile, BK=32, 512 threads = 8 waves (2M x 4N), per-wave 128x64 out.
// LDS: ring of 4 K-tile buffers (4 x (16K A + 16K B) = 128 KiB).
// Phase t: [vmcnt(8); s_barrier; sched_barrier; stage tile t+3 -> buf (t+3)&3;
//           12 ds_read_b128 from buf t&3; setprio(1); 32 MFMA; setprio(0)].
// Race-freedom: stage of t+3 targets buf (t-1)&3; every wave completed its
// phase-(t-1) ds_reads of that buffer (lgkmcnt before its MFMAs) before it
// arrived at phase-t's barrier, and the overwrite is issued only after that
// barrier.  vmcnt(8) = 2 tiles x 4 loads/thread allowed in flight -> tile t
// resident before any read; barrier extends the guarantee to all waves.
// T2 swizzle (both-sides, rule #21): gload dest stays LINEAR; global source
// column pre-swizzled (ko = ((c&3)^((c>>3)&3))*8); ds_read uses
// quad^((r>>1)&3) -> bank groups (r&1)*4+(quad^((r>>1)&3)) cover all 8.
// ---------------------------------------------------------------------------
__device__ static inline void stage32(const u16* __restrict__ A, const u16* __restrict__ Bm,
                                      u16* dA, u16* dB, int mb, int nbT, int kt, int tid) {
#pragma unroll
    for (int s = 0; s < 2; ++s) {
        int c = tid + s * 512;                       // 16B chunk id, 0..1023
        int row = c >> 2;                            // 0..255
        int ko = ((c & 3) ^ ((c >> 3) & 3)) * 8;     // inverse-swizzled source col
        gload16(A + (size_t)(mb + row) * K_DIM + kt + ko, (char*)dA + c * 16);
        gload16(Bm + (size_t)(nbT + row) * K_DIM + kt + ko, (char*)dB + c * 16);
    }
}

__global__ __launch_bounds__(512, 2) void gemm_lstm(const u16* __restrict__ A,
                                                    const u16* __restrict__ Bm,
                                                    const float* __restrict__ c_prev,
                                                    const float* __restrict__ bf_,
                                                    const float* __restrict__ bi_,
                                                    const float* __restrict__ bc_,
                                                    const float* __restrict__ bo_,
                                                    float* __restrict__ out) {
    __shared__ __align__(16) u16 lsA[4][256 * 32];   // 64 KiB
    __shared__ __align__(16) u16 lsB[4][256 * 32];   // 64 KiB

    const int tid  = threadIdx.x;
    const int lane = tid & 63;
    const int wave = tid >> 6;
    const int wm2  = (wave >> 2) * 128;   // M half (0/128)
    const int wn2  = (wave & 3) * 64;     // N quarter (0/64/128/192)
    const int quad = lane >> 4;           // 0..3 (k-slice)
    const int r    = lane & 15;           // 0..15
    const int qsw  = (quad ^ ((r >> 1) & 3)) * 8;   // swizzled chunk, in elems
    const int mb   = blockIdx.y * 256;    // batch tile
    const int nbT  = blockIdx.x * 256;    // wb row tile

    floatx4 acc[8][4];
#pragma unroll
    for (int i = 0; i < 8; ++i)
#pragma unroll
        for (int g = 0; g < 4; ++g)
            acc[i][g] = (floatx4){0.f, 0.f, 0.f, 0.f};

    // Prologue: stage tiles 0,1,2 (12 loads/thread outstanding).
#pragma unroll
    for (int pt = 0; pt < 3; ++pt)
        stage32(A, Bm, lsA[pt], lsB[pt], mb, nbT, pt * 32, tid);

#pragma unroll 4
    for (int t = 0; t < 128; ++t) {
        if (t < 126) {
            asm volatile("s_waitcnt vmcnt(8)" ::: "memory");   // counted, never drain
        } else {
            asm volatile("s_waitcnt vmcnt(0)" ::: "memory");   // epilogue drain (2 iters)
        }
        __builtin_amdgcn_s_barrier();
        __builtin_amdgcn_sched_barrier(0);   // nothing crosses the phase boundary

        if (t < 125)
            stage32(A, Bm, lsA[(t + 3) & 3], lsB[(t + 3) & 3], mb, nbT, (t + 3) * 32, tid);

        const u16* sA = lsA[t & 3];
        const u16* sB = lsB[t & 3];
        bf16x8 af[8], bb[4];
#pragma unroll
        for (int i = 0; i < 8; ++i)
            af[i] = *(const bf16x8*)&sA[(wm2 + i * 16 + r) * 32 + qsw];
#pragma unroll
        for (int g = 0; g < 4; ++g)
            bb[g] = *(const bf16x8*)&sB[(wn2 + g * 16 + r) * 32 + qsw];

        __builtin_amdgcn_s_setprio(1);
#pragma unroll
        for (int i = 0; i < 8; ++i)
#pragma unroll
            for (int g = 0; g < 4; ++g)
                acc[i][g] = __builtin_amdgcn_mfma_f32_16x16x32_bf16(
                    af[i], bb[g], acc[i][g], 0, 0, 0);
        __builtin_amdgcn_s_setprio(0);
    }

    // Fence: keep epilogue-only state out of the K-loop's live range.
    __builtin_amdgcn_sched_barrier(0);

    // In-register LSTM epilogue.
    // C/D layout: col = lane&15, row = quad*4 + reg.  Gate-permuted wb gives
    // frag g = gate g of j = bx*64 + (wave&3)*16 + r (verified all 4 quarters).
    const int j = blockIdx.x * 64 + (wave & 3) * 16 + r;
    const float bfv = bf_[j], biv = bi_[j], bcv = bc_[j], bov = bo_[j];
    const int rowb = mb + wm2 + quad * 4;
    const float* cp = c_prev + (size_t)rowb * H_DIM + j;
    float* oh = out + (size_t)rowb * H_DIM + j;
    float* oc = oh + (size_t)B_DIM * H_DIM;
#pragma unroll
    for (int i = 0; i < 8; ++i) {
#pragma unroll
        for (int rg = 0; rg < 4; ++rg) {
            size_t off = (size_t)(i * 16 + rg) * H_DIM;
            float gf = acc[i][0][rg] + bfv;
            float gi = acc[i][1][rg] + biv;
            float gc = acc[i][2][rg] + bcv;
            float go = acc[i][3][rg] + bov;
            float f  = fast_sig(gf);
            float ii = fast_sig(gi);
            float ct = fast_tanh(gc);
            float oo = fast_sig(go);
            float c  = f * cp[off] + ii * ct;
            float h  = oo * fast_tanh(c);
            oh[off] = h;
            oc[off] = c;
        }
    }
}

// ---------------------------------------------------------------------------
// Fallback (only if ws_size < 96 MiB): naive fp32, correct but slow.
// ---------------------------------------------------------------------------
__global__ void lstm_naive(const float* __restrict__ x_t, const float* __restrict__ h_prev,
                           const float* __restrict__ c_prev,
                           const float* __restrict__ Wf, const float* __restrict__ bf_,
                           const float* __restrict__ Wi, const float* __restrict__ bi_,
                           const float* __restrict__ Wc, const float* __restrict__ bc_,
                           const float* __restrict__ Wo, const float* __restrict__ bo_,
                           float* __restrict__ out) {
    int j = blockIdx.x * blockDim.x + threadIdx.x;  // 0..2047
    int b = blockIdx.y;                             // 0..4095
    const float* hrow = h_prev + (long long)b * H_DIM;
    const float* xrow = x_t   + (long long)b * I_DIM;
    const float* wf = Wf + (long long)j * K_DIM;
    const float* wi = Wi + (long long)j * K_DIM;
    const float* wc = Wc + (long long)j * K_DIM;
    const float* wo = Wo + (long long)j * K_DIM;
    float af = bf_[j], ai = bi_[j], ac = bc_[j], ao = bo_[j];
    for (int k = 0; k < H_DIM; k += 4) {
        float4 v = *(const float4*)(hrow + k);
        float4 a = *(const float4*)(wf + k);
        float4 bqi = *(const float4*)(wi + k);
        float4 cq = *(const float4*)(wc + k);
        float4 dq = *(const float4*)(wo + k);
        af += v.x*a.x + v.y*a.y + v.z*a.z + v.w*a.w;
        ai += v.x*bqi.x + v.y*bqi.y + v.z*bqi.z + v.w*bqi.w;
        ac += v.x*cq.x + v.y*cq.y + v.z*cq.z + v.w*cq.w;
        ao += v.x*dq.x + v.y*dq.y + v.z*dq.z + v.w*dq.w;
    }
    for (int k = 0; k < I_DIM; k += 4) {
        float4 v = *(const float4*)(xrow + k);
        float4 a = *(const float4*)(wf + H_DIM + k);
        float4 bqi = *(const float4*)(wi + H_DIM + k);
        float4 cq = *(const float4*)(wc + H_DIM + k);
        float4 dq = *(const float4*)(wo + H_DIM + k);
        af += v.x*a.x + v.y*a.y + v.z*a.z + v.w*a.w;
        ai += v.x*bqi.x + v.y*bqi.y + v.z*bqi.z + v.w*bqi.w;
        ac += v.x*cq.x + v.y*cq.y + v.z*cq.z + v.w*cq.w;
        ao += v.x*dq.x + v.y*dq.y + v.z*dq.z + v.w*dq.w;
    }
    float f  = 1.f / (1.f + __expf(-af));
    float ii = 1.f / (1.f + __expf(-ai));
    float ct = tanhf(ac);
    float oo = 1.f / (1.f + __expf(-ao));
    int t = b * H_DIM + j;
    float c = f * c_prev[t] + ii * ct;
    out[t] = oo * tanhf(c);
    out[B_DIM * H_DIM + t] = c;
}

extern "C" void kernel_launch(void* const* d_in, const int* in_sizes, int n_in,
                              void* d_out, int out_size, void* d_ws, size_t ws_size,
                              hipStream_t stream) {
    const float* x_t    = (const float*)d_in[0];
    const float* h_prev = (const float*)d_in[1];
    const float* c_prev = (const float*)d_in[2];
    const float* Wf = (const float*)d_in[3];  const float* bf_ = (const float*)d_in[4];
    const float* Wi = (const float*)d_in[5];  const float* bi_ = (const float*)d_in[6];
    const float* Wc = (const float*)d_in[7];  const float* bc_ = (const float*)d_in[8];
    const float* Wo = (const float*)d_in[9];  const float* bo_ = (const float*)d_in[10];
    float* out = (float*)d_out;

    const size_t comb_elems = (size_t)B_DIM * K_DIM;   // 16.7M u16
    const size_t wb_elems   = (size_t)N4 * K_DIM;      // 33.5M u16
    const size_t need = (comb_elems + wb_elems) * sizeof(u16);  // 96 MiB

    if (ws_size >= need) {
        u16* comb = (u16*)d_ws;
        u16* wb   = comb + comb_elems;
        convert_all<<<24576, 256, 0, stream>>>(h_prev, x_t, Wf, Wi, Wc, Wo, comb, wb);
        dim3 grid(N4 / 256, B_DIM / 256);  // (32, 16)
        gemm_lstm<<<grid, 512, 0, stream>>>(comb, wb, c_prev, bf_, bi_, bc_, bo_, out);
    } else {
        dim3 grid(H_DIM / 256, B_DIM);
        lstm_naive<<<grid, 256, 0, stream>>>(x_t, h_prev, c_prev,
                                             Wf, bf_, Wi, bi_, Wc, bc_, Wo, bo_, out);
    }
}